// Round 15
// baseline (774.821 us; speedup 1.0000x reference)
//
#include <hip/hip_runtime.h>
#include <hip/hip_bf16.h>
#include <math.h>

// GeometricNodeClassifier on MI355X — round 15 (= r14 resubmitted: GPU was
// unavailable, bucket-fill experiment never ran; re-audited).
//
// MFMA GEMM + two-phase bucket CSR fill.
//
// History: r4 652us -> r6 520 (parallel scan) -> r8 457 (separable layer-0
// table) -> r9 563 REGRESSION (bf16 gemm-epilogue stores: WRITE 14x inflated)
// -> r11 421 (f32 epilogue + bf16 gather plane; isolation) -> r13 352 (MFMA
// GEMM: gemm left top-5). r13 profile: fill_kernel 51us, WRITE 54.6MB for a
// 3.2MB payload = 64B-line write-allocate per random 4B store (same family
// as r9). Fix: two-phase bucket fill. Bucket = tgt>>8 (196 buckets = scan
// blocks; bucket CSR region = [offsets[b*256], offsets[(b+1)*256]) so
// scan_final emits bpos for free). Phase A scatters 8B recs into 196
// sequential tails (lines fill before eviction); phase B re-scatters within
// each bucket's ~16KB L2-resident CSR window.

#define N_NODES 50000
#define N_EDGES 800000
#define SCAN_NBLK ((N_NODES + 255) / 256)   // 196 (= bucket count)

typedef __attribute__((ext_vector_type(8))) short bf16x8;
typedef __attribute__((ext_vector_type(4))) float f32x4;

__device__ __forceinline__ float eluf(float v) {
    return v > 0.0f ? v : expm1f(v);
}
__device__ __forceinline__ float b2f(unsigned short u) {
    union { unsigned int i; float f; } v; v.i = ((unsigned int)u) << 16; return v.f;
}
__device__ __forceinline__ unsigned short f2b(float f) {   // RNE
    union { float f; unsigned int i; } v; v.f = f;
    return (unsigned short)((v.i + 0x7FFFu + ((v.i >> 16) & 1u)) >> 16);
}

// ---------------- in-degree count + per-node combo id ----------------
__global__ __launch_bounds__(256) void count_combo_kernel(
        const int* __restrict__ tgt, const int* __restrict__ x,
        int* __restrict__ cnt, int* __restrict__ combo, int E) {
    int i = blockIdx.x * 256 + threadIdx.x;
    if (i < E) atomicAdd(&cnt[tgt[i]], 1);
    if (i < N_NODES)
        combo[i] = x[i * 3] * 64 + x[i * 3 + 1] * 8 + x[i * 3 + 2];
}

// ---------------- parallel exclusive scan ----------------
__global__ __launch_bounds__(256) void scan_part_kernel(const int* __restrict__ cnt,
        int* __restrict__ part) {
    int i = blockIdx.x * 256 + threadIdx.x;
    int v = (i < N_NODES) ? cnt[i] : 0;
    #pragma unroll
    for (int o = 32; o > 0; o >>= 1) v += __shfl_down(v, o, 64);
    __shared__ int ws[4];
    if ((threadIdx.x & 63) == 0) ws[threadIdx.x >> 6] = v;
    __syncthreads();
    if (threadIdx.x == 0) part[blockIdx.x] = ws[0] + ws[1] + ws[2] + ws[3];
}

__global__ __launch_bounds__(256) void scan_top_kernel(int* __restrict__ part) {
    __shared__ int tmp[256];
    int t = threadIdx.x;
    int v = (t < SCAN_NBLK) ? part[t] : 0;
    tmp[t] = v;
    __syncthreads();
    for (int o = 1; o < 256; o <<= 1) {
        int u = (t >= o) ? tmp[t - o] : 0;
        __syncthreads();
        tmp[t] += u;
        __syncthreads();
    }
    if (t < SCAN_NBLK) part[t] = tmp[t] - v;   // exclusive
}

// also emits bpos[b] = offsets[b*256] (bucket write pointers for binA)
__global__ __launch_bounds__(256) void scan_final_kernel(const int* __restrict__ cnt,
        const int* __restrict__ part, int* __restrict__ offsets,
        int* __restrict__ pos, int* __restrict__ bpos) {
    __shared__ int tmp[256];
    int i = blockIdx.x * 256 + threadIdx.x;
    int t = threadIdx.x;
    int v = (i < N_NODES) ? cnt[i] : 0;
    tmp[t] = v;
    __syncthreads();
    for (int o = 1; o < 256; o <<= 1) {
        int u = (t >= o) ? tmp[t - o] : 0;
        __syncthreads();
        tmp[t] += u;
        __syncthreads();
    }
    int excl = tmp[t] - v + part[blockIdx.x];
    if (i < N_NODES) { offsets[i] = excl; pos[i] = excl; }
    if (t == 0) bpos[blockIdx.x] = excl;       // offsets[b*256]
    if (i == 0) offsets[N_NODES] = N_EDGES;
}

// ---------------- fill phase A: bucket-scatter {tgt, payload} ----------------
// 196 sequential write tails -> 64B lines fill before eviction.
__global__ __launch_bounds__(256) void binA_kernel(const int* __restrict__ src,
        const int* __restrict__ tgt, const int* __restrict__ combo,
        int* __restrict__ bpos, int2* __restrict__ rec) {
    int e = blockIdx.x * 256 + threadIdx.x;
    if (e < N_EDGES) {
        int t = tgt[e], s = src[e];
        int p = atomicAdd(&bpos[t >> 8], 1);
        rec[p] = make_int2(t, s | (combo[s] << 16));
    }
}

// ---------------- fill phase B: within-bucket scatter to exact CSR slots -------
// consecutive threads read the same bucket; oc writes land in its ~16KB window.
__global__ __launch_bounds__(256) void binB_kernel(const int2* __restrict__ rec,
        int* __restrict__ pos, int* __restrict__ oc) {
    int p = blockIdx.x * 256 + threadIdx.x;
    if (p < N_EDGES) {
        int2 r = rec[p];
        int slot = atomicAdd(&pos[r.x], 1);
        oc[slot] = r.y;
    }
}

// ---------------- P tables: P[t*8+v][c] = emb_t[v] . [w_rel0|w_root0] seg t -------
__global__ __launch_bounds__(256) void ptab_kernel(const float* __restrict__ e0,
        const float* __restrict__ e1, const float* __restrict__ e2,
        const float* __restrict__ wrel, const float* __restrict__ wroot,
        float* __restrict__ P) {
    const int b = blockIdx.x;            // 0..23
    const int t = b >> 3, v = b & 7;
    const float* emb = (t == 0) ? e0 : (t == 1 ? e1 : e2);
    const float* erow = &emb[v * 200];
    const int c = threadIdx.x;           // 0..255
    const float* W = (c < 128) ? wrel : wroot;
    const float* Wp = &W[(size_t)(t * 200) * 128 + (c & 127)];
    __shared__ float es[200];
    for (int k = threadIdx.x; k < 200; k += 256) es[k] = erow[k];
    __syncthreads();
    float a0 = 0.f, a1 = 0.f;
    #pragma unroll 8
    for (int k = 0; k < 200; k += 2) {
        a0 = fmaf(es[k],     Wp[(size_t)k * 128],       a0);
        a1 = fmaf(es[k + 1], Wp[(size_t)(k + 1) * 128], a1);
    }
    P[(size_t)b * 256 + c] = a0 + a1;
}

// ---------------- Ycb[q] = bf16(P0[q>>6] + P1[(q>>3)&7] + P2[q&7]) ------------
__global__ __launch_bounds__(256) void ytab_kernel(const float* __restrict__ P,
        unsigned short* __restrict__ Ycb) {
    const int q = blockIdx.x;            // 0..511
    const int c = threadIdx.x;           // 0..255
    const float p0 = P[(size_t)(q >> 6) * 256 + c];
    const float p1 = P[(size_t)(8 + ((q >> 3) & 7)) * 256 + c];
    const float p2 = P[(size_t)(16 + (q & 7)) * 256 + c];
    Ycb[(size_t)q * 256 + c] = f2b(p0 + p1 + p2);
}

// ---------------- pack weights to MFMA fragment order (bf16) ----------------
// Bp[mat][ks][ct][lane][i] = bf16(W[ks*32 + 8*(lane>>4) + i][ct*16 + (lane&15)])
__global__ __launch_bounds__(64) void pack_kernel(const float* __restrict__ w1r,
        const float* __restrict__ w1t, const float* __restrict__ w2r,
        const float* __restrict__ w2t, unsigned short* __restrict__ Bp) {
    const int b = blockIdx.x, l = threadIdx.x;
    const int mat = b >> 5, ks = (b >> 3) & 3, ct = b & 7;
    const float* W = (mat == 0) ? w1r : (mat == 1) ? w1t : (mat == 2) ? w2r : w2t;
    const int col = ct * 16 + (l & 15);
    const int krow = ks * 32 + 8 * (l >> 4);
    unsigned short v[8];
    #pragma unroll
    for (int i = 0; i < 8; ++i)
        v[i] = f2b(W[(size_t)(krow + i) * 128 + col]);
    unsigned short* dst = &Bp[(size_t)((((mat * 4 + ks) * 8 + ct) * 64 + l) * 8)];
    #pragma unroll
    for (int i = 0; i < 8; ++i) dst[i] = v[i];
}

// ---------------- MFMA GEMM: {Yrel,Yroot}[M,128] = Xb[M,128] @ Wplane ----------
__global__ __launch_bounds__(256) void gemm_mfma(
        const unsigned short* __restrict__ Xb, const unsigned short* __restrict__ Bp,
        int matbase, float* __restrict__ Yrel, float* __restrict__ Yroot, int M) {
    const int plane = blockIdx.y;
    const unsigned short* Bpm = Bp + (size_t)(matbase + plane) * 4 * 8 * 64 * 8;
    float* __restrict__ Yp = plane ? Yroot : Yrel;
    const int w = threadIdx.x >> 6;
    const int l = threadIdx.x & 63;
    const int rbase = blockIdx.x * 128 + w * 32;
    const int arow0 = min(rbase + (l & 15), M - 1);
    const int arow1 = min(rbase + 16 + (l & 15), M - 1);
    const int kl = 8 * (l >> 4);
    f32x4 acc[2][8] = {};
    #pragma unroll
    for (int ks = 0; ks < 4; ++ks) {
        const int k0 = ks * 32 + kl;
        bf16x8 a0 = *(const bf16x8*)&Xb[(size_t)arow0 * 128 + k0];
        bf16x8 a1 = *(const bf16x8*)&Xb[(size_t)arow1 * 128 + k0];
        const unsigned short* bbase = Bpm + (size_t)ks * 8 * 64 * 8 + (size_t)l * 8;
        #pragma unroll
        for (int ct = 0; ct < 8; ++ct) {
            bf16x8 bf = *(const bf16x8*)&bbase[(size_t)ct * 64 * 8];
            acc[0][ct] = __builtin_amdgcn_mfma_f32_16x16x32_bf16(a0, bf, acc[0][ct], 0, 0, 0);
            acc[1][ct] = __builtin_amdgcn_mfma_f32_16x16x32_bf16(a1, bf, acc[1][ct], 0, 0, 0);
        }
    }
    // C/D layout (m89-verified): col = lane&15, row = (lane>>4)*4 + reg
    const int colb = l & 15;
    const int rowoff = (l >> 4) * 4;
    #pragma unroll
    for (int rt = 0; rt < 2; ++rt) {
        #pragma unroll
        for (int j = 0; j < 4; ++j) {
            const int row = rbase + rt * 16 + rowoff + j;
            if (row < M) {
                #pragma unroll
                for (int ct = 0; ct < 8; ++ct)
                    Yp[(size_t)row * 128 + ct * 16 + colb] = acc[rt][ct][j];
            }
        }
    }
}

// ---------------- layer-0 aggregate from the bf16 combo table -> bf16 X ---------
__global__ __launch_bounds__(256) void aggregate0_kernel(
        const unsigned short* __restrict__ Ycb, const int* __restrict__ oc,
        const int* __restrict__ combo, const int* __restrict__ offsets,
        const float* __restrict__ b, unsigned short* __restrict__ Xn) {
    int idx = blockIdx.x * 256 + threadIdx.x;
    int node = idx >> 5;
    int c = (idx & 31) * 4;
    if (node >= N_NODES) return;
    const int beg = offsets[node], end = offsets[node + 1];
    float ax = 0.f, ay = 0.f, az = 0.f, aw = 0.f;
    float gx = 0.f, gy = 0.f, gz = 0.f, gw = 0.f;
    int j = beg;
    for (; j + 3 < end; j += 4) {
        int q0 = oc[j] >> 16, q1 = oc[j + 1] >> 16;
        int q2 = oc[j + 2] >> 16, q3 = oc[j + 3] >> 16;
        ushort4 u0 = *(const ushort4*)&Ycb[(size_t)q0 * 256 + c];
        ushort4 u1 = *(const ushort4*)&Ycb[(size_t)q1 * 256 + c];
        ushort4 u2 = *(const ushort4*)&Ycb[(size_t)q2 * 256 + c];
        ushort4 u3 = *(const ushort4*)&Ycb[(size_t)q3 * 256 + c];
        ax += b2f(u0.x) + b2f(u1.x); ay += b2f(u0.y) + b2f(u1.y);
        az += b2f(u0.z) + b2f(u1.z); aw += b2f(u0.w) + b2f(u1.w);
        gx += b2f(u2.x) + b2f(u3.x); gy += b2f(u2.y) + b2f(u3.y);
        gz += b2f(u2.z) + b2f(u3.z); gw += b2f(u2.w) + b2f(u3.w);
    }
    for (; j < end; ++j) {
        int q0 = oc[j] >> 16;
        ushort4 u0 = *(const ushort4*)&Ycb[(size_t)q0 * 256 + c];
        ax += b2f(u0.x); ay += b2f(u0.y); az += b2f(u0.z); aw += b2f(u0.w);
    }
    float sx = ax + gx, sy = ay + gy, sz = az + gz, sw = aw + gw;
    const float inv = 1.0f / fmaxf((float)(end - beg), 1.0f);
    ushort4 ur = *(const ushort4*)&Ycb[(size_t)combo[node] * 256 + 128 + c];
    float4 bb = *(const float4*)&b[c];
    ushort4 o;
    o.x = f2b(eluf(fmaf(sx, inv, bb.x) + b2f(ur.x)));
    o.y = f2b(eluf(fmaf(sy, inv, bb.y) + b2f(ur.y)));
    o.z = f2b(eluf(fmaf(sz, inv, bb.z) + b2f(ur.z)));
    o.w = f2b(eluf(fmaf(sw, inv, bb.w) + b2f(ur.w)));
    *(ushort4*)&Xn[(size_t)node * 128 + c] = o;
}

// ---------------- layers 1/2 aggregate: gather bf16 rel, stream f32 root -> bf16 X
__global__ __launch_bounds__(256) void aggregate_kernel(
        const unsigned short* __restrict__ Ybrel, const float* __restrict__ Yroot,
        const int* __restrict__ oc, const int* __restrict__ offsets,
        const float* __restrict__ b, unsigned short* __restrict__ Xn) {
    int idx = blockIdx.x * 256 + threadIdx.x;
    int node = idx >> 5;
    int c = (idx & 31) * 4;
    if (node >= N_NODES) return;
    const int beg = offsets[node], end = offsets[node + 1];
    float ax = 0.f, ay = 0.f, az = 0.f, aw = 0.f;
    float gx = 0.f, gy = 0.f, gz = 0.f, gw = 0.f;
    int j = beg;
    for (; j + 3 < end; j += 4) {
        int s0 = oc[j] & 0xFFFF, s1 = oc[j + 1] & 0xFFFF;
        int s2 = oc[j + 2] & 0xFFFF, s3 = oc[j + 3] & 0xFFFF;
        ushort4 u0 = *(const ushort4*)&Ybrel[(size_t)s0 * 128 + c];
        ushort4 u1 = *(const ushort4*)&Ybrel[(size_t)s1 * 128 + c];
        ushort4 u2 = *(const ushort4*)&Ybrel[(size_t)s2 * 128 + c];
        ushort4 u3 = *(const ushort4*)&Ybrel[(size_t)s3 * 128 + c];
        ax += b2f(u0.x) + b2f(u1.x); ay += b2f(u0.y) + b2f(u1.y);
        az += b2f(u0.z) + b2f(u1.z); aw += b2f(u0.w) + b2f(u1.w);
        gx += b2f(u2.x) + b2f(u3.x); gy += b2f(u2.y) + b2f(u3.y);
        gz += b2f(u2.z) + b2f(u3.z); gw += b2f(u2.w) + b2f(u3.w);
    }
    for (; j < end; ++j) {
        int s0 = oc[j] & 0xFFFF;
        ushort4 u0 = *(const ushort4*)&Ybrel[(size_t)s0 * 128 + c];
        ax += b2f(u0.x); ay += b2f(u0.y); az += b2f(u0.z); aw += b2f(u0.w);
    }
    float sx = ax + gx, sy = ay + gy, sz = az + gz, sw = aw + gw;
    const float inv = 1.0f / fmaxf((float)(end - beg), 1.0f);
    float4 yr = *(const float4*)&Yroot[(size_t)node * 128 + c];
    float4 bb = *(const float4*)&b[c];
    ushort4 o;
    o.x = f2b(eluf(fmaf(sx, inv, bb.x) + yr.x));
    o.y = f2b(eluf(fmaf(sy, inv, bb.y) + yr.y));
    o.z = f2b(eluf(fmaf(sz, inv, bb.z) + yr.z));
    o.w = f2b(eluf(fmaf(sw, inv, bb.w) + yr.w));
    *(ushort4*)&Xn[(size_t)node * 128 + c] = o;
}

// ---------------- convert: f32 rel plane -> bf16 rel plane ----------------
__global__ __launch_bounds__(256) void conv_kernel(const float* __restrict__ Yf,
        unsigned short* __restrict__ Yb) {
    int i = blockIdx.x * 256 + threadIdx.x;      // over N*128/8 = 800000
    if (i >= N_NODES * 16) return;
    float4 a = ((const float4*)Yf)[(size_t)i * 2];
    float4 b = ((const float4*)Yf)[(size_t)i * 2 + 1];
    uint4 w;
    w.x = (unsigned int)f2b(a.x) | ((unsigned int)f2b(a.y) << 16);
    w.y = (unsigned int)f2b(a.z) | ((unsigned int)f2b(a.w) << 16);
    w.z = (unsigned int)f2b(b.x) | ((unsigned int)f2b(b.y) << 16);
    w.w = (unsigned int)f2b(b.z) | ((unsigned int)f2b(b.w) << 16);
    ((uint4*)Yb)[i] = w;
}

// ---------------- output head: out = X(bf16) @ w_out + b_out ----------------
__global__ __launch_bounds__(256) void out_kernel(const unsigned short* __restrict__ X,
        const float* __restrict__ W, const float* __restrict__ bo,
        float* __restrict__ out, int M) {
    __shared__ float Ws[128 * 32];
    const int tid = threadIdx.x;
    #pragma unroll
    for (int o = tid * 4; o < 4096; o += 1024)
        *(float4*)&Ws[o] = *(const float4*)&W[o];
    __syncthreads();
    const int row = blockIdx.x * 32 + (tid >> 3);
    const int col = (tid & 7) * 4;
    if (row >= M) return;
    float a0 = 0.f, a1 = 0.f, a2 = 0.f, a3 = 0.f;
    for (int k8 = 0; k8 < 16; ++k8) {
        ushort4 xl = *(const ushort4*)&X[(size_t)row * 128 + k8 * 8];
        ushort4 xh = *(const ushort4*)&X[(size_t)row * 128 + k8 * 8 + 4];
        float xa[8] = {b2f(xl.x), b2f(xl.y), b2f(xl.z), b2f(xl.w),
                       b2f(xh.x), b2f(xh.y), b2f(xh.z), b2f(xh.w)};
        #pragma unroll
        for (int j = 0; j < 8; ++j) {
            float4 wv = *(const float4*)&Ws[(k8 * 8 + j) * 32 + col];
            a0 = fmaf(xa[j], wv.x, a0);
            a1 = fmaf(xa[j], wv.y, a1);
            a2 = fmaf(xa[j], wv.z, a2);
            a3 = fmaf(xa[j], wv.w, a3);
        }
    }
    float4 bb = *(const float4*)&bo[col];
    *(float4*)&out[(size_t)row * 32 + col] =
        make_float4(a0 + bb.x, a1 + bb.y, a2 + bb.z, a3 + bb.w);
}

extern "C" void kernel_launch(void* const* d_in, const int* in_sizes, int n_in,
                              void* d_out, int out_size, void* d_ws, size_t ws_size,
                              hipStream_t stream) {
    const int* x        = (const int*)d_in[0];
    const int* ei       = (const int*)d_in[1];
    const float* e0     = (const float*)d_in[2];
    const float* e1     = (const float*)d_in[3];
    const float* e2     = (const float*)d_in[4];
    const float* w_rel0 = (const float*)d_in[5];
    const float* w_root0= (const float*)d_in[6];
    const float* b0     = (const float*)d_in[7];
    const float* w_rel1 = (const float*)d_in[8];
    const float* w_root1= (const float*)d_in[9];
    const float* b1     = (const float*)d_in[10];
    const float* w_rel2 = (const float*)d_in[11];
    const float* w_root2= (const float*)d_in[12];
    const float* b2     = (const float*)d_in[13];
    const float* w_out  = (const float*)d_in[14];
    const float* b_out  = (const float*)d_in[15];
    float* out = (float*)d_out;

    const int N = N_NODES, E = N_EDGES;
    // workspace layout (~87.6 MB, 16B-aligned)
    char* base = (char*)d_ws;
    float*          Yrel = (float*)base;                         // [N,128] f32
    float*          Yroot= (float*)(base + 25600000);            // [N,128] f32
    unsigned short* Xb   = (unsigned short*)(base + 51200000);   // [N,128] bf16
    unsigned short* H    = (unsigned short*)(base + 64000000);   // [N,128] bf16
    int*            oc   = (int*)(base + 76800000);              // [E] packed
    int2*           rec  = (int2*)(base + 80000000);             // [E] {tgt,payload}
    unsigned short* Bp   = (unsigned short*)(base + 86400000);   // [4][4][8][64][8] bf16
    float*          P    = (float*)(base + 86531072);            // [24,256] f32
    unsigned short* Ycb  = (unsigned short*)(base + 86555648);   // [512,256] bf16
    int*            cnt     = (int*)(base + 86817792);           // [N]
    int*            offsets = cnt + N;                           // [N+1]
    int*            pos     = offsets + N + 1;                   // [N]
    int*            combo   = pos + N;                           // [N]
    int*            part    = combo + N;                         // [SCAN_NBLK]
    int*            bpos    = part + SCAN_NBLK;                  // [SCAN_NBLK]

    const int* src = ei;
    const int* tgt = ei + E;

    // --- CSR build + combo ids ---
    hipMemsetAsync(cnt, 0, N * sizeof(int), stream);
    count_combo_kernel<<<(E + 255) / 256, 256, 0, stream>>>(tgt, x, cnt, combo, E);
    scan_part_kernel<<<SCAN_NBLK, 256, 0, stream>>>(cnt, part);
    scan_top_kernel<<<1, 256, 0, stream>>>(part);
    scan_final_kernel<<<SCAN_NBLK, 256, 0, stream>>>(cnt, part, offsets, pos, bpos);
    binA_kernel<<<(E + 255) / 256, 256, 0, stream>>>(src, tgt, combo, bpos, rec);
    binB_kernel<<<(E + 255) / 256, 256, 0, stream>>>(rec, pos, oc);

    // --- layer-0 combo table (separable) + weight pack ---
    ptab_kernel<<<24, 256, 0, stream>>>(e0, e1, e2, w_rel0, w_root0, P);
    ytab_kernel<<<512, 256, 0, stream>>>(P, Ycb);
    pack_kernel<<<128, 64, 0, stream>>>(w_rel1, w_root1, w_rel2, w_root2, Bp);

    const int agg_grid = (N * 32 + 255) / 256;
    const int conv_grid = (N * 16 + 255) / 256;
    dim3 ggrid((N + 127) / 128, 2);

    // --- layer 0 -> Xb ---
    aggregate0_kernel<<<agg_grid, 256, 0, stream>>>(Ycb, oc, combo, offsets, b0, Xb);

    // --- layer 1: Xb -> (Yrel, Yroot) -> H -> Xb ---
    gemm_mfma<<<ggrid, 256, 0, stream>>>(Xb, Bp, 0, Yrel, Yroot, N);
    conv_kernel<<<conv_grid, 256, 0, stream>>>(Yrel, H);
    aggregate_kernel<<<agg_grid, 256, 0, stream>>>(H, Yroot, oc, offsets, b1, Xb);

    // --- layer 2 ---
    gemm_mfma<<<ggrid, 256, 0, stream>>>(Xb, Bp, 2, Yrel, Yroot, N);
    conv_kernel<<<conv_grid, 256, 0, stream>>>(Yrel, H);
    aggregate_kernel<<<agg_grid, 256, 0, stream>>>(H, Yroot, oc, offsets, b2, Xb);

    out_kernel<<<(N + 31) / 32, 256, 0, stream>>>(Xb, w_out, b_out, out, N);
}